// Round 7
// baseline (433.944 us; speedup 1.0000x reference)
//
#include <hip/hip_runtime.h>
#include <hip/hip_fp16.h>
#include <cstddef>
#include <cstdint>

#define DIM 128
#define SEQ 2048
#define NB 32
#define NCH 512
#define NROWS (NB * SEQ)          // 65536

typedef _Float16 half8 __attribute__((ext_vector_type(8)));
typedef float    f32x4 __attribute__((ext_vector_type(4)));

// ws layout: cmb fp16 frag-pages [4096 pages][8192] | Wfg | barrier cells
// page p = rowblk*8 + kb  (rowblk = global_row/128, kb = k/64)
// in-page: rt7*1024 + ks*512 + qq*128 + m*8 + j
//   rt7=(row>>4)&7, m=row&15, ks=(k>>5)&1, qq=(k>>3)&3, j=k&7
#define CMB_BYTES ((size_t)NROWS * NCH * 2)       // 67,108,864
#define WFG_OFF   CMB_BYTES
#define WFG_BYTES ((size_t)NCH * DIM * 2)         // 131,072
#define BAR_OFF   (WFG_OFF + WFG_BYTES)
#define WS_NEEDED (BAR_OFF + 64)

// fast sigmoid: raw v_exp + raw v_rcp (no Newton refinement)
__device__ __forceinline__ float sigf(float v) {
    return __builtin_amdgcn_rcpf(1.0f + __builtin_amdgcn_exp2f(v * -1.44269504f));
}

// packed fp32x8 -> fp16x8 via v_cvt_pkrtz_f16_f32
__device__ __forceinline__ half8 cvt8(float4 v0, float4 v1) {
    auto p0 = __builtin_amdgcn_cvt_pkrtz(v0.x, v0.y);
    auto p1 = __builtin_amdgcn_cvt_pkrtz(v0.z, v0.w);
    auto p2 = __builtin_amdgcn_cvt_pkrtz(v1.x, v1.y);
    auto p3 = __builtin_amdgcn_cvt_pkrtz(v1.z, v1.w);
    union U { half8 h8; decltype(p0) p[4]; } u;
    u.p[0] = p0; u.p[1] = p1; u.p[2] = p2; u.p[3] = p3;
    return u.h8;
}

// async global->LDS, 16B per lane (wave-uniform LDS base + lane*16)
__device__ __forceinline__ void gload_lds16(const _Float16* g, _Float16* l) {
    __builtin_amdgcn_global_load_lds(
        (const __attribute__((address_space(1))) void*)g,
        (__attribute__((address_space(3))) void*)l,
        16, 0, 0);
}

// ---------------------------------------------------------------------------
// kmega: Phase A = kfused v13 (byte-identical math) -> software grid barrier
//        -> Phase B = k3 v2 GEMM re-waved for 512 threads (8 waves).
// Co-residency proof: grid=512, __launch_bounds__(512,2), 64 KB LDS/block ->
//   2 blocks/CU x 256 CU = 512 slots >= grid, so all blocks are resident and
//   the arrival-counter spin cannot deadlock. Counter is memset to 0 on the
//   stream before each launch (graph-replay safe).
// ---------------------------------------------------------------------------
__global__ __launch_bounds__(512, 2) void kmega(
        const float* __restrict__ x,
        const float* __restrict__ Wa_u, const float* __restrict__ ba_u,
        const float* __restrict__ Wi_u, const float* __restrict__ bi_u,
        const float* __restrict__ g_u,
        const float* __restrict__ Wa_w, const float* __restrict__ ba_w,
        const float* __restrict__ Wi_w, const float* __restrict__ bi_w,
        const float* __restrict__ g_w,
        const float* __restrict__ Wf, const float* __restrict__ bfv,
        _Float16* __restrict__ Wfg, _Float16* __restrict__ cmb,
        float* __restrict__ out, unsigned* __restrict__ bar) {
    __shared__ __align__(16) char smem[65536];   // overlaid phase A / phase B

    // phase A views (20.9 KB)
    _Float16* Bs    = (_Float16*)smem;                    // 16 KB
    float2*   wseg  = (float2*)(smem + 16384);            // [2][8][33] = 4224 B
    float*    carry = (float*)(smem + 16384 + 4224);      // [2][32] = 256 B

    const int tid  = threadIdx.x;
    const int lane = tid & 63;
    const int w    = tid >> 6;           // wave 0..7
    const int quad = lane >> 4;
    const int n16  = lane & 15;

    const int id = blockIdx.x;           // 0..511
    const int b  = id & 31;              // batch
    const int cg = id >> 5;              // 0..15
    const int p  = cg >> 3;              // path
    const int ebase = (cg & 7) * 32;     // 32 channels per block

    // ---- fused k0 pre-pass: the 16 blocks with b==0 transform Wf -> Wfg ----
    if (b == 0) {
        int tg = cg * 512 + tid;          // 0..8191
#pragma unroll
        for (int i = 0; i < 8; ++i) {
            int o = tg * 8 + i;           // 65536 total
            int j    = o & 7;
            int l2   = (o >> 3) & 63;
            int q2   = l2 >> 4, m16 = l2 & 15;
            int ct   = (o >> 9) & 7;
            int ks2  = (o >> 12) & 1;
            int kb2  = o >> 13;
            int k = kb2 * 64 + ks2 * 32 + q2 * 8 + j;
            int n = ct * 16 + m16;
            Wfg[o] = (_Float16)Wf[n * NCH + k];
        }
    }

    const float* Wa  = p ? Wa_w : Wa_u;
    const float* Wi  = p ? Wi_w : Wi_u;
    const float* bap = p ? ba_w : ba_u;
    const float* bip = p ? bi_w : bi_u;
    const float* gp  = p ? g_w  : g_u;

    // ---- stage Bs once: slot sl = ks*256 + nt*64 + l (1024 slots, 2/thread)
    for (int sl = tid; sl < 1024; sl += 512) {
        int l  = sl & 63;
        int nt = (sl >> 6) & 3;
        int ks = sl >> 8;
        int qq = l >> 4, nn = l & 15;
        int e = ebase + (nt & 1) * 16 + nn;
        const float* Wp = (nt >> 1) ? Wi : Wa;
        const float* src = Wp + (size_t)e * DIM + ks * 32 + qq * 8;
        float4 v0 = *(const float4*)src;
        float4 v1 = *(const float4*)(src + 4);
        *(half8*)&Bs[sl * 8] = cvt8(v0, v1);
    }

    // per-thread channel params (hh = 0/1 -> ch = hh*16 + n16)
    const float NL2E = -1.44269504f;
    float rba[2], rbi[2], ral[2], rba2[2];
#pragma unroll
    for (int hh = 0; hh < 2; ++hh) {
        int e = ebase + hh * 16 + n16;
        rba[hh] = bap[e];
        rbi[hh] = bip[e];
        ral[hh] = sigf(gp[e]);
        rba2[hh] = rba[hh] * NL2E;
    }
    if (tid < 32) carry[tid] = 0.0f;

    // incremental recency weight: sc(s) = exp(3s/2047)
    float scb = __expf((float)(w * 16 + quad * 4) * (3.0f / 2047.0f));
    const float r1    = __expf(3.0f / 2047.0f);
    const float r2    = r1 * r1;
    const float r3    = r2 * r1;
    const float cs128 = __expf(128.0f * 3.0f / 2047.0f);

    // A-row for this lane: s_local = w*16 + n16 (= MFMA m index)
    const float* xbase = x + ((size_t)b * SEQ + (size_t)(w * 16 + n16)) * DIM + quad * 8;
    // fragment-page store base: page = (b*16+t)*8 + (cg>>1)
    _Float16* dst0 = cmb + (size_t)(cg >> 1) * 8192 + (size_t)w * 1024
                   + (size_t)(cg & 1) * 512
                   + (size_t)quad * 32 + (size_t)(n16 >> 3) * 128 + (n16 & 7);

    __syncthreads();                     // Bs + carry init visible

    // ---- prologue: registerize B-frags for ks 0,1 (constant all tiles) ----
    half8 bfr[8];
#pragma unroll
    for (int ks = 0; ks < 2; ++ks)
#pragma unroll
        for (int nt = 0; nt < 4; ++nt)
            bfr[ks * 4 + nt] = *(const half8*)&Bs[(ks * 256 + nt * 64 + lane) * 8];

    // ---- prologue: load + convert tile 0's A-frags ----
    half8 af[4];
    {
        float4 xf0[8];
#pragma unroll
        for (int ks = 0; ks < 4; ++ks) {
            xf0[2 * ks]     = *(const float4*)(xbase + ks * 32);
            xf0[2 * ks + 1] = *(const float4*)(xbase + ks * 32 + 4);
        }
#pragma unroll
        for (int ks = 0; ks < 4; ++ks)
            af[ks] = cvt8(xf0[2 * ks], xf0[2 * ks + 1]);
    }

    for (int t = 0; t < 16; ++t) {
        // ---- MFMA: 4 n-tiles, K=128; ks 0,1 B from regs, ks 2,3 from LDS --
        f32x4 acc[4];
#pragma unroll
        for (int nt = 0; nt < 4; ++nt) acc[nt] = (f32x4){0.f, 0.f, 0.f, 0.f};
#pragma unroll
        for (int ks = 0; ks < 4; ++ks) {
            half8 a = af[ks];
#pragma unroll
            for (int nt = 0; nt < 4; ++nt) {
                half8 bb = (ks < 2)
                    ? bfr[ks * 4 + nt]
                    : *(const half8*)&Bs[(ks * 256 + nt * 64 + lane) * 8];
                acc[nt] = __builtin_amdgcn_mfma_f32_16x16x32_f16(a, bb, acc[nt], 0, 0, 0);
            }
        }

        // ---- issue FIRST HALF of next tile's A loads (long flight) ----
        const float* ab = xbase + (size_t)((t + 1) & 15) * 128 * DIM;
        float4 xf1[4];
#pragma unroll
        for (int ks = 0; ks < 2; ++ks) {
            xf1[2 * ks]     = *(const float4*)(ab + ks * 32);
            xf1[2 * ks + 1] = *(const float4*)(ab + ks * 32 + 4);
        }

        // ---- gates + 4-step affine compose (2 channels) ----
        float sc[4], sc2[4];
        if (p) { sc[0] = scb; sc[1] = scb * r1; sc[2] = scb * r2; sc[3] = scb * r3; }
        else   { sc[0] = sc[1] = sc[2] = sc[3] = 1.0f; }
        scb *= cs128;
#pragma unroll
        for (int reg = 0; reg < 4; ++reg) sc2[reg] = sc[reg] * NL2E;

        float a_s[2][4], u_s[2][4];
        float IA[2], IU[2], EA[2], EU[2];
#pragma unroll
        for (int hh = 0; hh < 2; ++hh) {
            float A4 = 1.0f, U4 = 0.0f;
#pragma unroll
            for (int reg = 0; reg < 4; ++reg) {
                float pi  = fmaf(acc[2 + hh][reg], sc[reg], rbi[hh]);
                float ea  = __builtin_amdgcn_exp2f(fmaf(acc[hh][reg], sc2[reg], rba2[hh]));
                float rst = __builtin_amdgcn_rcpf(1.0f + ea);
                float ig  = sigf(pi);
                float a   = ral[hh] * __builtin_amdgcn_exp2f(-rst * 1.5849625007211562f);
                float m   = fmaxf(fmaf(-a, a, 1.0f), 0.0f);
                float u   = __builtin_amdgcn_sqrtf(m) * (ig * pi);
                a_s[hh][reg] = a; u_s[hh][reg] = u;
                A4 *= a;
                U4 = fmaf(a, U4, u);
            }
            // Kogge-Stone inclusive scan over quads (lane stride 16)
            float A = A4, U = U4;
            float Ap = __shfl_up(A, 16); float Up = __shfl_up(U, 16);
            bool c1 = quad >= 1;
            U = c1 ? fmaf(A, Up, U) : U;
            A = c1 ? A * Ap : A;
            Ap = __shfl_up(A, 32); Up = __shfl_up(U, 32);
            bool c2 = quad >= 2;
            U = c2 ? fmaf(A, Up, U) : U;
            A = c2 ? A * Ap : A;
            IA[hh] = A; IU[hh] = U;                 // inclusive prefix
            float Ae = __shfl_up(A, 16), Ue = __shfl_up(U, 16);
            EA[hh] = (quad == 0) ? 1.0f : Ae;       // exclusive prefix
            EU[hh] = (quad == 0) ? 0.0f : Ue;
        }
        if (quad == 3) {
#pragma unroll
            for (int hh = 0; hh < 2; ++hh)
                wseg[((t & 1) * 8 + w) * 33 + hh * 16 + n16] = make_float2(IA[hh], IU[hh]);
        }

        __syncthreads();   // the ONLY barrier: wseg (and prev carry) visible

        // ---- issue SECOND HALF of next tile's A loads ----
        float4 xf2[4];
#pragma unroll
        for (int ks = 0; ks < 2; ++ks) {
            xf2[2 * ks]     = *(const float4*)(ab + 64 + ks * 32);
            xf2[2 * ks + 1] = *(const float4*)(ab + 64 + ks * 32 + 4);
        }
        // convert first half now (data long in flight)
        af[0] = cvt8(xf1[0], xf1[1]);
        af[1] = cvt8(xf1[2], xf1[3]);

        // ---- per-lane compose (batched loads) + replay + store ----
        _Float16* dstT = dst0 + (size_t)((b * 16 + t) * 8) * 8192;
#pragma unroll
        for (int hh = 0; hh < 2; ++hh) {
            int ch = hh * 16 + n16;
            float h = carry[(t & 1) * 32 + ch];
            float2 wv[7];
#pragma unroll
            for (int jj = 0; jj < 7; ++jj)
                wv[jj] = wseg[((t & 1) * 8 + jj) * 33 + ch];   // independent loads
#pragma unroll
            for (int jj = 0; jj < 7; ++jj)
                if (jj < w) h = fmaf(wv[jj].x, h, wv[jj].y);
            // apply exclusive quad prefix
            h = fmaf(EA[hh], h, EU[hh]);
            // replay 4 steps + store in fragment-page layout
#pragma unroll
            for (int reg = 0; reg < 4; ++reg) {
                h = fmaf(a_s[hh][reg], h, u_s[hh][reg]);
                dstT[hh * 256 + reg * 8] = (_Float16)h;
            }
            if (w == 7 && quad == 3)
                carry[((t + 1) & 1) * 32 + ch] = h;  // tile-final h = next carry
        }

        // convert second half (flight covered by compose/replay)
        af[2] = cvt8(xf2[0], xf2[1]);
        af[3] = cvt8(xf2[2], xf2[3]);
    }

    // =======================================================================
    // software grid barrier (all 512 blocks co-resident by construction)
    // =======================================================================
    __syncthreads();                         // block's phase-A work done
    __threadfence();                         // device-scope release of cmb/Wfg
    if (tid == 0) {
        __hip_atomic_fetch_add(bar, 1u, __ATOMIC_ACQ_REL, __HIP_MEMORY_SCOPE_AGENT);
        unsigned v;
        do {
            __builtin_amdgcn_s_sleep(8);
            v = __hip_atomic_load(bar, __ATOMIC_ACQUIRE, __HIP_MEMORY_SCOPE_AGENT);
        } while (v < 512u);
    }
    __syncthreads();                         // whole block released together
    __threadfence();                         // acquire side

    // =======================================================================
    // Phase B: k3 v2 GEMM, 8 waves. rowblk = blockIdx.x, 128 rows x 128 N,
    //   K=512 in 8 pages; As/Bs double-buffered (64 KB overlay), gload_lds16.
    // =======================================================================
    {
        _Float16* AsB = (_Float16*)smem;              // [2][8192]
        _Float16* BsB = (_Float16*)(smem + 32768);    // [2][8192]
        const int rb   = id;                 // row-block 0..511
        const int row0 = rb * 128;
        const int q    = quad;
        const int nn   = n16;

        f32x4 acc2[8];
#pragma unroll
        for (int ct = 0; ct < 8; ++ct) acc2[ct] = (f32x4){0.f, 0.f, 0.f, 0.f};

        // wave w stages elements [w*1024, w*1024+1024) of each 8192-elem page
#define MSTAGE(buf, kb)                                                       \
        {                                                                     \
            const _Float16* sa = cmb + ((size_t)rb * 8 + (kb)) * 8192         \
                               + (size_t)w * 1024 + (size_t)lane * 8;         \
            const _Float16* sb = Wfg + (size_t)(kb) * 8192                    \
                               + (size_t)w * 1024 + (size_t)lane * 8;         \
            _Float16* la = AsB + (buf) * 8192 + w * 1024;                     \
            _Float16* lb = BsB + (buf) * 8192 + w * 1024;                     \
            gload_lds16(sa, la);       gload_lds16(sa + 512, la + 512);       \
            gload_lds16(sb, lb);       gload_lds16(sb + 512, lb + 512);       \
        }

        MSTAGE(0, 0);
        __syncthreads();                     // implies vmcnt(0) drain

        for (int kb = 0; kb < 8; ++kb) {
            const int cur = kb & 1;
            if (kb < 7) MSTAGE(cur ^ 1, kb + 1);

#pragma unroll
            for (int ks = 0; ks < 2; ++ks) {
                half8 a = *(const half8*)&AsB[cur * 8192 + (w * 2 + ks) * 512 + lane * 8];
#pragma unroll
                for (int ct = 0; ct < 8; ++ct) {
                    half8 bb = *(const half8*)&BsB[cur * 8192 + (ks * 8 + ct) * 512 + lane * 8];
                    acc2[ct] = __builtin_amdgcn_mfma_f32_16x16x32_f16(a, bb, acc2[ct], 0, 0, 0);
                }
            }
            __syncthreads();                 // next buf staged + cur reusable
        }

        const int rbase = row0 + w * 16 + q * 4;
#pragma unroll
        for (int ct = 0; ct < 8; ++ct) {
            int col = ct * 16 + nn;
            float bias = bfv[col];
#pragma unroll
            for (int reg = 0; reg < 4; ++reg)
                out[(size_t)(rbase + reg) * DIM + col] = acc2[ct][reg] + bias;
        }
#undef MSTAGE
    }
}

// ---------------------------------------------------------------------------
extern "C" void kernel_launch(void* const* d_in, const int* in_sizes, int n_in,
                              void* d_out, int out_size, void* d_ws, size_t ws_size,
                              hipStream_t stream) {
    if (ws_size < WS_NEEDED) return;

    const float* x    = (const float*)d_in[0];
    const float* Wa_u = (const float*)d_in[1];
    const float* ba_u = (const float*)d_in[2];
    const float* Wi_u = (const float*)d_in[3];
    const float* bi_u = (const float*)d_in[4];
    const float* g_u  = (const float*)d_in[5];
    const float* Wa_w = (const float*)d_in[6];
    const float* ba_w = (const float*)d_in[7];
    const float* Wi_w = (const float*)d_in[8];
    const float* bi_w = (const float*)d_in[9];
    const float* g_w  = (const float*)d_in[10];
    const float* Wf   = (const float*)d_in[11];
    const float* bfv  = (const float*)d_in[12];
    float* out = (float*)d_out;

    char* ws = (char*)d_ws;
    _Float16* cmb = (_Float16*)ws;
    _Float16* Wfg = (_Float16*)(ws + WFG_OFF);
    unsigned* bar = (unsigned*)(ws + BAR_OFF);

    hipMemsetAsync(bar, 0, 8, stream);       // zero arrival counter (replay-safe)
    hipLaunchKernelGGL(kmega, dim3(512), dim3(512), 0, stream,
                       x, Wa_u, ba_u, Wi_u, bi_u, g_u,
                       Wa_w, ba_w, Wi_w, bi_w, g_w,
                       Wf, bfv, Wfg, cmb, out, bar);
}

// Round 8
// 206.758 us; speedup vs baseline: 2.0988x; 2.0988x over previous
//
#include <hip/hip_runtime.h>
#include <hip/hip_fp16.h>
#include <cstddef>
#include <cstdint>

#define DIM 128
#define SEQ 2048
#define NB 32
#define NCH 512
#define NROWS (NB * SEQ)          // 65536

typedef _Float16 half8 __attribute__((ext_vector_type(8)));
typedef float    f32x4 __attribute__((ext_vector_type(4)));

// ws layout: cmb fp16 frag-pages [4096 pages][8192] | Wfg fp16 frag-linear
// page p = rowblk*8 + kb  (rowblk = global_row/128, kb = k/64)
// in-page: rt7*1024 + ks*512 + qq*128 + m*8 + j
//   rt7=(row>>4)&7, m=row&15, ks=(k>>5)&1, qq=(k>>3)&3, j=k&7
#define CMB_BYTES ((size_t)NROWS * NCH * 2)       // 67,108,864
#define WFG_OFF   CMB_BYTES
#define WFG_BYTES ((size_t)NCH * DIM * 2)         // 131,072
#define WS_NEEDED (WFG_OFF + WFG_BYTES)

// fast sigmoid: raw v_exp + raw v_rcp (no Newton refinement)
__device__ __forceinline__ float sigf(float v) {
    return __builtin_amdgcn_rcpf(1.0f + __builtin_amdgcn_exp2f(v * -1.44269504f));
}

// packed fp32x8 -> fp16x8 via v_cvt_pkrtz_f16_f32
__device__ __forceinline__ half8 cvt8(float4 v0, float4 v1) {
    auto p0 = __builtin_amdgcn_cvt_pkrtz(v0.x, v0.y);
    auto p1 = __builtin_amdgcn_cvt_pkrtz(v0.z, v0.w);
    auto p2 = __builtin_amdgcn_cvt_pkrtz(v1.x, v1.y);
    auto p3 = __builtin_amdgcn_cvt_pkrtz(v1.z, v1.w);
    union U { half8 h8; decltype(p0) p[4]; } u;
    u.p[0] = p0; u.p[1] = p1; u.p[2] = p2; u.p[3] = p3;
    return u.h8;
}

// async global->LDS, 16B per lane (wave-uniform LDS base + lane*16)
__device__ __forceinline__ void gload_lds16(const _Float16* g, _Float16* l) {
    __builtin_amdgcn_global_load_lds(
        (const __attribute__((address_space(1))) void*)g,
        (__attribute__((address_space(3))) void*)l,
        16, 0, 0);
}

// ---------------------------------------------------------------------------
// kfused v13 (round-6 best, byte-identical): v12 core + fused k0 pre-pass
//   (the 16 blocks with blockIdx.x==0 write Wfg = Wf pre-swizzled; only k3
//   reads Wfg and k3 launches after kfused on the same stream).
// ---------------------------------------------------------------------------
__global__ __launch_bounds__(512, 2) void kfused(
        const float* __restrict__ x,
        const float* __restrict__ Wa_u, const float* __restrict__ ba_u,
        const float* __restrict__ Wi_u, const float* __restrict__ bi_u,
        const float* __restrict__ g_u,
        const float* __restrict__ Wa_w, const float* __restrict__ ba_w,
        const float* __restrict__ Wi_w, const float* __restrict__ bi_w,
        const float* __restrict__ g_w,
        const float* __restrict__ Wf, _Float16* __restrict__ Wfg,
        _Float16* __restrict__ cmb) {
    __shared__ _Float16 Bs[8192];        // [ks(4)][nt(4)][lane(64)][8] = 16 KB
    __shared__ float2   Wseg[2][8][33];  // per-wave composite (dbuf)
    __shared__ float    carryL[2][32];   // running h per channel (dbuf)

    const int tid  = threadIdx.x;
    const int lane = tid & 63;
    const int w    = tid >> 6;           // wave 0..7 = m-tile (16 s each)
    const int quad = lane >> 4;
    const int n16  = lane & 15;

    const int b  = blockIdx.x;           // 0..31
    const int cg = blockIdx.y;           // 0..15
    const int p  = cg >> 3;              // path
    const int ebase = (cg & 7) * 32;     // 32 channels per block

    // ---- fused k0 pre-pass: blocks (0, cg) transform Wf -> Wfg ----
    if (b == 0) {
        int tg = cg * 512 + tid;          // 0..8191
#pragma unroll
        for (int i = 0; i < 8; ++i) {
            int o = tg * 8 + i;           // 65536 total
            int j    = o & 7;
            int l2   = (o >> 3) & 63;
            int q2   = l2 >> 4, m16 = l2 & 15;
            int ct   = (o >> 9) & 7;
            int ks2  = (o >> 12) & 1;
            int kb2  = o >> 13;
            int k = kb2 * 64 + ks2 * 32 + q2 * 8 + j;
            int n = ct * 16 + m16;
            Wfg[o] = (_Float16)Wf[n * NCH + k];
        }
    }

    const float* Wa  = p ? Wa_w : Wa_u;
    const float* Wi  = p ? Wi_w : Wi_u;
    const float* bap = p ? ba_w : ba_u;
    const float* bip = p ? bi_w : bi_u;
    const float* gp  = p ? g_w  : g_u;

    // ---- stage Bs once: slot sl = ks*256 + nt*64 + l (1024 slots, 2/thread)
    for (int sl = tid; sl < 1024; sl += 512) {
        int l  = sl & 63;
        int nt = (sl >> 6) & 3;
        int ks = sl >> 8;
        int qq = l >> 4, nn = l & 15;
        int e = ebase + (nt & 1) * 16 + nn;
        const float* Wp = (nt >> 1) ? Wi : Wa;
        const float* src = Wp + (size_t)e * DIM + ks * 32 + qq * 8;
        float4 v0 = *(const float4*)src;
        float4 v1 = *(const float4*)(src + 4);
        *(half8*)&Bs[sl * 8] = cvt8(v0, v1);
    }

    // per-thread channel params (hh = 0/1 -> ch = hh*16 + n16)
    const float NL2E = -1.44269504f;
    float rba[2], rbi[2], ral[2], rba2[2];
#pragma unroll
    for (int hh = 0; hh < 2; ++hh) {
        int e = ebase + hh * 16 + n16;
        rba[hh] = bap[e];
        rbi[hh] = bip[e];
        ral[hh] = sigf(gp[e]);
        rba2[hh] = rba[hh] * NL2E;
    }
    if (tid < 32) carryL[0][tid] = 0.0f;

    // incremental recency weight: sc(s) = exp(3s/2047)
    float scb = __expf((float)(w * 16 + quad * 4) * (3.0f / 2047.0f));
    const float r1    = __expf(3.0f / 2047.0f);
    const float r2    = r1 * r1;
    const float r3    = r2 * r1;
    const float cs128 = __expf(128.0f * 3.0f / 2047.0f);

    // A-row for this lane: s_local = w*16 + n16 (= MFMA m index)
    const float* xbase = x + ((size_t)b * SEQ + (size_t)(w * 16 + n16)) * DIM + quad * 8;
    // fragment-page store base: page = (b*16+t)*8 + (cg>>1)
    _Float16* dst0 = cmb + (size_t)(cg >> 1) * 8192 + (size_t)w * 1024
                   + (size_t)(cg & 1) * 512
                   + (size_t)quad * 32 + (size_t)(n16 >> 3) * 128 + (n16 & 7);

    __syncthreads();                     // Bs + carry init visible

    // ---- prologue: registerize B-frags for ks 0,1 (constant all tiles) ----
    half8 bfr[8];
#pragma unroll
    for (int ks = 0; ks < 2; ++ks)
#pragma unroll
        for (int nt = 0; nt < 4; ++nt)
            bfr[ks * 4 + nt] = *(const half8*)&Bs[(ks * 256 + nt * 64 + lane) * 8];

    // ---- prologue: load + convert tile 0's A-frags ----
    half8 af[4];
    {
        float4 xf0[8];
#pragma unroll
        for (int ks = 0; ks < 4; ++ks) {
            xf0[2 * ks]     = *(const float4*)(xbase + ks * 32);
            xf0[2 * ks + 1] = *(const float4*)(xbase + ks * 32 + 4);
        }
#pragma unroll
        for (int ks = 0; ks < 4; ++ks)
            af[ks] = cvt8(xf0[2 * ks], xf0[2 * ks + 1]);
    }

    for (int t = 0; t < 16; ++t) {
        // ---- MFMA: 4 n-tiles, K=128; ks 0,1 B from regs, ks 2,3 from LDS --
        f32x4 acc[4];
#pragma unroll
        for (int nt = 0; nt < 4; ++nt) acc[nt] = (f32x4){0.f, 0.f, 0.f, 0.f};
#pragma unroll
        for (int ks = 0; ks < 4; ++ks) {
            half8 a = af[ks];
#pragma unroll
            for (int nt = 0; nt < 4; ++nt) {
                half8 bb = (ks < 2)
                    ? bfr[ks * 4 + nt]
                    : *(const half8*)&Bs[(ks * 256 + nt * 64 + lane) * 8];
                acc[nt] = __builtin_amdgcn_mfma_f32_16x16x32_f16(a, bb, acc[nt], 0, 0, 0);
            }
        }

        // ---- issue FIRST HALF of next tile's A loads (long flight) ----
        const float* ab = xbase + (size_t)((t + 1) & 15) * 128 * DIM;
        float4 xf1[4];
#pragma unroll
        for (int ks = 0; ks < 2; ++ks) {
            xf1[2 * ks]     = *(const float4*)(ab + ks * 32);
            xf1[2 * ks + 1] = *(const float4*)(ab + ks * 32 + 4);
        }

        // ---- gates + 4-step affine compose (2 channels) ----
        float sc[4], sc2[4];
        if (p) { sc[0] = scb; sc[1] = scb * r1; sc[2] = scb * r2; sc[3] = scb * r3; }
        else   { sc[0] = sc[1] = sc[2] = sc[3] = 1.0f; }
        scb *= cs128;
#pragma unroll
        for (int reg = 0; reg < 4; ++reg) sc2[reg] = sc[reg] * NL2E;

        float a_s[2][4], u_s[2][4];
        float IA[2], IU[2], EA[2], EU[2];
#pragma unroll
        for (int hh = 0; hh < 2; ++hh) {
            float A4 = 1.0f, U4 = 0.0f;
#pragma unroll
            for (int reg = 0; reg < 4; ++reg) {
                float pi  = fmaf(acc[2 + hh][reg], sc[reg], rbi[hh]);
                float ea  = __builtin_amdgcn_exp2f(fmaf(acc[hh][reg], sc2[reg], rba2[hh]));
                float rst = __builtin_amdgcn_rcpf(1.0f + ea);
                float ig  = sigf(pi);
                float a   = ral[hh] * __builtin_amdgcn_exp2f(-rst * 1.5849625007211562f);
                float m   = fmaxf(fmaf(-a, a, 1.0f), 0.0f);
                float u   = __builtin_amdgcn_sqrtf(m) * (ig * pi);
                a_s[hh][reg] = a; u_s[hh][reg] = u;
                A4 *= a;
                U4 = fmaf(a, U4, u);
            }
            // Kogge-Stone inclusive scan over quads (lane stride 16)
            float A = A4, U = U4;
            float Ap = __shfl_up(A, 16); float Up = __shfl_up(U, 16);
            bool c1 = quad >= 1;
            U = c1 ? fmaf(A, Up, U) : U;
            A = c1 ? A * Ap : A;
            Ap = __shfl_up(A, 32); Up = __shfl_up(U, 32);
            bool c2 = quad >= 2;
            U = c2 ? fmaf(A, Up, U) : U;
            A = c2 ? A * Ap : A;
            IA[hh] = A; IU[hh] = U;                 // inclusive prefix
            float Ae = __shfl_up(A, 16), Ue = __shfl_up(U, 16);
            EA[hh] = (quad == 0) ? 1.0f : Ae;       // exclusive prefix
            EU[hh] = (quad == 0) ? 0.0f : Ue;
        }
        if (quad == 3) {
#pragma unroll
            for (int hh = 0; hh < 2; ++hh)
                Wseg[t & 1][w][hh * 16 + n16] = make_float2(IA[hh], IU[hh]);
        }

        __syncthreads();   // the ONLY barrier: Wseg (and prev carry) visible

        // ---- issue SECOND HALF of next tile's A loads ----
        float4 xf2[4];
#pragma unroll
        for (int ks = 0; ks < 2; ++ks) {
            xf2[2 * ks]     = *(const float4*)(ab + 64 + ks * 32);
            xf2[2 * ks + 1] = *(const float4*)(ab + 64 + ks * 32 + 4);
        }
        // convert first half now (data long in flight)
        af[0] = cvt8(xf1[0], xf1[1]);
        af[1] = cvt8(xf1[2], xf1[3]);

        // ---- per-lane compose (batched loads) + replay + store ----
        _Float16* dstT = dst0 + (size_t)((b * 16 + t) * 8) * 8192;
#pragma unroll
        for (int hh = 0; hh < 2; ++hh) {
            int ch = hh * 16 + n16;
            float h = carryL[t & 1][ch];
            float2 wv[7];
#pragma unroll
            for (int jj = 0; jj < 7; ++jj)
                wv[jj] = Wseg[t & 1][jj][ch];       // independent loads first
#pragma unroll
            for (int jj = 0; jj < 7; ++jj)
                if (jj < w) h = fmaf(wv[jj].x, h, wv[jj].y);
            // apply exclusive quad prefix
            h = fmaf(EA[hh], h, EU[hh]);
            // replay 4 steps + store in fragment-page layout
#pragma unroll
            for (int reg = 0; reg < 4; ++reg) {
                h = fmaf(a_s[hh][reg], h, u_s[hh][reg]);
                dstT[hh * 256 + reg * 8] = (_Float16)h;
            }
            if (w == 7 && quad == 3)
                carryL[(t + 1) & 1][ch] = h;        // tile-final h = next carry
        }

        // convert second half (flight covered by compose/replay)
        af[2] = cvt8(xf2[0], xf2[1]);
        af[3] = cvt8(xf2[2], xf2[3]);
    }
}

// ---------------------------------------------------------------------------
// k3 v4: OCCUPANCY for the GEMM. 64-row tiles -> grid 1024 = 4 blocks/CU
//   (was 2), 16 waves/CU. Bs LDS eliminated: Wfg (128 KB) is L2-resident and
//   read directly into VGPRs per page (compiler-scoreboarded, hidden by TLP).
//   As stays gload_lds-staged + double-buffered, WAVE-PRIVATE slices
//   (wave w stages exactly the rt7 = half*4+w slice it consumes).
//   LDS 16 KB, __launch_bounds__(256,4) caps VGPR at 128.
// ---------------------------------------------------------------------------
__global__ __launch_bounds__(256, 4) void k3_mfma(
        const _Float16* __restrict__ cmbF, const _Float16* __restrict__ Wfg,
        const float* __restrict__ bfv, float* __restrict__ out) {
    __shared__ _Float16 As[2][4096];     // 2 x 8 KB, wave-private 1024-elem slices

    const int tid  = threadIdx.x;
    const int lane = tid & 63;
    const int w    = tid >> 6;           // wave 0..3
    const int id   = blockIdx.x;         // 0..1023
    const int rb   = id >> 1;            // 128-row page group
    const int half = id & 1;             // which 64 rows
    const int rt7  = half * 4 + w;       // this wave's 16-row slice (0..7)
    const int q    = lane >> 4;
    const int nn   = lane & 15;

    f32x4 acc[8];
#pragma unroll
    for (int ct = 0; ct < 8; ++ct) acc[ct] = (f32x4){0.0f, 0.0f, 0.0f, 0.0f};

    // wave-private As slice: 1024 elems = 2 x gload_lds16 (512 elems each)
#define K3_STAGE(buf, kb)                                                     \
    {                                                                         \
        const _Float16* sa = cmbF + ((size_t)rb * 8 + (kb)) * 8192            \
                           + (size_t)rt7 * 1024 + (size_t)lane * 8;           \
        _Float16* la = &As[buf][w * 1024];                                    \
        gload_lds16(sa, la);                                                  \
        gload_lds16(sa + 512, la + 512);                                      \
    }

    K3_STAGE(0, 0);
    __syncthreads();                     // implies vmcnt(0) drain

    for (int kb = 0; kb < 8; ++kb) {
        const int cur = kb & 1;
        if (kb < 7) K3_STAGE(cur ^ 1, kb + 1);

        const _Float16* bsrc = Wfg + (size_t)kb * 8192 + (size_t)lane * 8;
#pragma unroll
        for (int ks = 0; ks < 2; ++ks) {
            half8 a = *(const half8*)&As[cur][w * 1024 + ks * 512 + lane * 8];
#pragma unroll
            for (int ct = 0; ct < 8; ++ct) {
                half8 bb = *(const half8*)(bsrc + (size_t)(ks * 8 + ct) * 512);
                acc[ct] = __builtin_amdgcn_mfma_f32_16x16x32_f16(a, bb, acc[ct], 0, 0, 0);
            }
        }
        __syncthreads();                 // next buf staged + cur free for reuse
    }

    const int rbase = rb * 128 + rt7 * 16 + q * 4;
#pragma unroll
    for (int ct = 0; ct < 8; ++ct) {
        int col = ct * 16 + nn;
        float bias = bfv[col];
#pragma unroll
        for (int reg = 0; reg < 4; ++reg)
            out[(size_t)(rbase + reg) * DIM + col] = acc[ct][reg] + bias;
    }
#undef K3_STAGE
}

// ---------------------------------------------------------------------------
extern "C" void kernel_launch(void* const* d_in, const int* in_sizes, int n_in,
                              void* d_out, int out_size, void* d_ws, size_t ws_size,
                              hipStream_t stream) {
    if (ws_size < WS_NEEDED) return;

    const float* x    = (const float*)d_in[0];
    const float* Wa_u = (const float*)d_in[1];
    const float* ba_u = (const float*)d_in[2];
    const float* Wi_u = (const float*)d_in[3];
    const float* bi_u = (const float*)d_in[4];
    const float* g_u  = (const float*)d_in[5];
    const float* Wa_w = (const float*)d_in[6];
    const float* ba_w = (const float*)d_in[7];
    const float* Wi_w = (const float*)d_in[8];
    const float* bi_w = (const float*)d_in[9];
    const float* g_w  = (const float*)d_in[10];
    const float* Wf   = (const float*)d_in[11];
    const float* bfv  = (const float*)d_in[12];
    float* out = (float*)d_out;

    char* ws = (char*)d_ws;
    _Float16* cmb = (_Float16*)ws;
    _Float16* Wfg = (_Float16*)(ws + WFG_OFF);

    hipLaunchKernelGGL(kfused, dim3(32, 16), dim3(512), 0, stream,
                       x, Wa_u, ba_u, Wi_u, bi_u, g_u,
                       Wa_w, ba_w, Wi_w, bi_w, g_w, Wf, Wfg, cmb);
    hipLaunchKernelGGL(k3_mfma, dim3(1024), dim3(256), 0, stream,
                       cmb, Wfg, bfv, out);
}

// Round 9
// 191.510 us; speedup vs baseline: 2.2659x; 1.0796x over previous
//
#include <hip/hip_runtime.h>
#include <hip/hip_fp16.h>
#include <cstddef>
#include <cstdint>

#define DIM 128
#define SEQ 2048
#define NB 32
#define NCH 512
#define NROWS (NB * SEQ)          // 65536

typedef _Float16 half8 __attribute__((ext_vector_type(8)));
typedef float    f32x4 __attribute__((ext_vector_type(4)));

// ws layout: cmb fp16 frag-pages [4096 pages][8192] | Wfg fp16 frag-linear
// page p = rowblk*8 + kb  (rowblk = global_row/128, kb = k/64)
// in-page: rt7*1024 + ks*512 + qq*128 + m*8 + j
//   rt7=(row>>4)&7, m=row&15, ks=(k>>5)&1, qq=(k>>3)&3, j=k&7
#define CMB_BYTES ((size_t)NROWS * NCH * 2)       // 67,108,864
#define WFG_OFF   CMB_BYTES
#define WFG_BYTES ((size_t)NCH * DIM * 2)         // 131,072
#define WS_NEEDED (WFG_OFF + WFG_BYTES)

// fast sigmoid: raw v_exp + raw v_rcp (no Newton refinement)
__device__ __forceinline__ float sigf(float v) {
    return __builtin_amdgcn_rcpf(1.0f + __builtin_amdgcn_exp2f(v * -1.44269504f));
}

// packed fp32x8 -> fp16x8 via v_cvt_pkrtz_f16_f32
__device__ __forceinline__ half8 cvt8(float4 v0, float4 v1) {
    auto p0 = __builtin_amdgcn_cvt_pkrtz(v0.x, v0.y);
    auto p1 = __builtin_amdgcn_cvt_pkrtz(v0.z, v0.w);
    auto p2 = __builtin_amdgcn_cvt_pkrtz(v1.x, v1.y);
    auto p3 = __builtin_amdgcn_cvt_pkrtz(v1.z, v1.w);
    union U { half8 h8; decltype(p0) p[4]; } u;
    u.p[0] = p0; u.p[1] = p1; u.p[2] = p2; u.p[3] = p3;
    return u.h8;
}

// async global->LDS, 16B per lane (wave-uniform LDS base + lane*16)
__device__ __forceinline__ void gload_lds16(const _Float16* g, _Float16* l) {
    __builtin_amdgcn_global_load_lds(
        (const __attribute__((address_space(1))) void*)g,
        (__attribute__((address_space(3))) void*)l,
        16, 0, 0);
}

// ---------------------------------------------------------------------------
// kfused v13 (round-6 best, byte-identical): v12 core + fused k0 pre-pass
//   (the 16 blocks with blockIdx.x==0 write Wfg = Wf pre-swizzled; only k3
//   reads Wfg and k3 launches after kfused on the same stream).
// ---------------------------------------------------------------------------
__global__ __launch_bounds__(512, 2) void kfused(
        const float* __restrict__ x,
        const float* __restrict__ Wa_u, const float* __restrict__ ba_u,
        const float* __restrict__ Wi_u, const float* __restrict__ bi_u,
        const float* __restrict__ g_u,
        const float* __restrict__ Wa_w, const float* __restrict__ ba_w,
        const float* __restrict__ Wi_w, const float* __restrict__ bi_w,
        const float* __restrict__ g_w,
        const float* __restrict__ Wf, _Float16* __restrict__ Wfg,
        _Float16* __restrict__ cmb) {
    __shared__ _Float16 Bs[8192];        // [ks(4)][nt(4)][lane(64)][8] = 16 KB
    __shared__ float2   Wseg[2][8][33];  // per-wave composite (dbuf)
    __shared__ float    carryL[2][32];   // running h per channel (dbuf)

    const int tid  = threadIdx.x;
    const int lane = tid & 63;
    const int w    = tid >> 6;           // wave 0..7 = m-tile (16 s each)
    const int quad = lane >> 4;
    const int n16  = lane & 15;

    const int b  = blockIdx.x;           // 0..31
    const int cg = blockIdx.y;           // 0..15
    const int p  = cg >> 3;              // path
    const int ebase = (cg & 7) * 32;     // 32 channels per block

    // ---- fused k0 pre-pass: blocks (0, cg) transform Wf -> Wfg ----
    if (b == 0) {
        int tg = cg * 512 + tid;          // 0..8191
#pragma unroll
        for (int i = 0; i < 8; ++i) {
            int o = tg * 8 + i;           // 65536 total
            int j    = o & 7;
            int l2   = (o >> 3) & 63;
            int q2   = l2 >> 4, m16 = l2 & 15;
            int ct   = (o >> 9) & 7;
            int ks2  = (o >> 12) & 1;
            int kb2  = o >> 13;
            int k = kb2 * 64 + ks2 * 32 + q2 * 8 + j;
            int n = ct * 16 + m16;
            Wfg[o] = (_Float16)Wf[n * NCH + k];
        }
    }

    const float* Wa  = p ? Wa_w : Wa_u;
    const float* Wi  = p ? Wi_w : Wi_u;
    const float* bap = p ? ba_w : ba_u;
    const float* bip = p ? bi_w : bi_u;
    const float* gp  = p ? g_w  : g_u;

    // ---- stage Bs once: slot sl = ks*256 + nt*64 + l (1024 slots, 2/thread)
    for (int sl = tid; sl < 1024; sl += 512) {
        int l  = sl & 63;
        int nt = (sl >> 6) & 3;
        int ks = sl >> 8;
        int qq = l >> 4, nn = l & 15;
        int e = ebase + (nt & 1) * 16 + nn;
        const float* Wp = (nt >> 1) ? Wi : Wa;
        const float* src = Wp + (size_t)e * DIM + ks * 32 + qq * 8;
        float4 v0 = *(const float4*)src;
        float4 v1 = *(const float4*)(src + 4);
        *(half8*)&Bs[sl * 8] = cvt8(v0, v1);
    }

    // per-thread channel params (hh = 0/1 -> ch = hh*16 + n16)
    const float NL2E = -1.44269504f;
    float rba[2], rbi[2], ral[2], rba2[2];
#pragma unroll
    for (int hh = 0; hh < 2; ++hh) {
        int e = ebase + hh * 16 + n16;
        rba[hh] = bap[e];
        rbi[hh] = bip[e];
        ral[hh] = sigf(gp[e]);
        rba2[hh] = rba[hh] * NL2E;
    }
    if (tid < 32) carryL[0][tid] = 0.0f;

    // incremental recency weight: sc(s) = exp(3s/2047)
    float scb = __expf((float)(w * 16 + quad * 4) * (3.0f / 2047.0f));
    const float r1    = __expf(3.0f / 2047.0f);
    const float r2    = r1 * r1;
    const float r3    = r2 * r1;
    const float cs128 = __expf(128.0f * 3.0f / 2047.0f);

    // A-row for this lane: s_local = w*16 + n16 (= MFMA m index)
    const float* xbase = x + ((size_t)b * SEQ + (size_t)(w * 16 + n16)) * DIM + quad * 8;
    // fragment-page store base: page = (b*16+t)*8 + (cg>>1)
    _Float16* dst0 = cmb + (size_t)(cg >> 1) * 8192 + (size_t)w * 1024
                   + (size_t)(cg & 1) * 512
                   + (size_t)quad * 32 + (size_t)(n16 >> 3) * 128 + (n16 & 7);

    __syncthreads();                     // Bs + carry init visible

    // ---- prologue: registerize B-frags for ks 0,1 (constant all tiles) ----
    half8 bfr[8];
#pragma unroll
    for (int ks = 0; ks < 2; ++ks)
#pragma unroll
        for (int nt = 0; nt < 4; ++nt)
            bfr[ks * 4 + nt] = *(const half8*)&Bs[(ks * 256 + nt * 64 + lane) * 8];

    // ---- prologue: load + convert tile 0's A-frags ----
    half8 af[4];
    {
        float4 xf0[8];
#pragma unroll
        for (int ks = 0; ks < 4; ++ks) {
            xf0[2 * ks]     = *(const float4*)(xbase + ks * 32);
            xf0[2 * ks + 1] = *(const float4*)(xbase + ks * 32 + 4);
        }
#pragma unroll
        for (int ks = 0; ks < 4; ++ks)
            af[ks] = cvt8(xf0[2 * ks], xf0[2 * ks + 1]);
    }

    for (int t = 0; t < 16; ++t) {
        // ---- MFMA: 4 n-tiles, K=128; ks 0,1 B from regs, ks 2,3 from LDS --
        f32x4 acc[4];
#pragma unroll
        for (int nt = 0; nt < 4; ++nt) acc[nt] = (f32x4){0.f, 0.f, 0.f, 0.f};
#pragma unroll
        for (int ks = 0; ks < 4; ++ks) {
            half8 a = af[ks];
#pragma unroll
            for (int nt = 0; nt < 4; ++nt) {
                half8 bb = (ks < 2)
                    ? bfr[ks * 4 + nt]
                    : *(const half8*)&Bs[(ks * 256 + nt * 64 + lane) * 8];
                acc[nt] = __builtin_amdgcn_mfma_f32_16x16x32_f16(a, bb, acc[nt], 0, 0, 0);
            }
        }

        // ---- issue FIRST HALF of next tile's A loads (long flight) ----
        const float* ab = xbase + (size_t)((t + 1) & 15) * 128 * DIM;
        float4 xf1[4];
#pragma unroll
        for (int ks = 0; ks < 2; ++ks) {
            xf1[2 * ks]     = *(const float4*)(ab + ks * 32);
            xf1[2 * ks + 1] = *(const float4*)(ab + ks * 32 + 4);
        }

        // ---- gates + 4-step affine compose (2 channels) ----
        float sc[4], sc2[4];
        if (p) { sc[0] = scb; sc[1] = scb * r1; sc[2] = scb * r2; sc[3] = scb * r3; }
        else   { sc[0] = sc[1] = sc[2] = sc[3] = 1.0f; }
        scb *= cs128;
#pragma unroll
        for (int reg = 0; reg < 4; ++reg) sc2[reg] = sc[reg] * NL2E;

        float a_s[2][4], u_s[2][4];
        float IA[2], IU[2], EA[2], EU[2];
#pragma unroll
        for (int hh = 0; hh < 2; ++hh) {
            float A4 = 1.0f, U4 = 0.0f;
#pragma unroll
            for (int reg = 0; reg < 4; ++reg) {
                float pi  = fmaf(acc[2 + hh][reg], sc[reg], rbi[hh]);
                float ea  = __builtin_amdgcn_exp2f(fmaf(acc[hh][reg], sc2[reg], rba2[hh]));
                float rst = __builtin_amdgcn_rcpf(1.0f + ea);
                float ig  = sigf(pi);
                float a   = ral[hh] * __builtin_amdgcn_exp2f(-rst * 1.5849625007211562f);
                float m   = fmaxf(fmaf(-a, a, 1.0f), 0.0f);
                float u   = __builtin_amdgcn_sqrtf(m) * (ig * pi);
                a_s[hh][reg] = a; u_s[hh][reg] = u;
                A4 *= a;
                U4 = fmaf(a, U4, u);
            }
            // Kogge-Stone inclusive scan over quads (lane stride 16)
            float A = A4, U = U4;
            float Ap = __shfl_up(A, 16); float Up = __shfl_up(U, 16);
            bool c1 = quad >= 1;
            U = c1 ? fmaf(A, Up, U) : U;
            A = c1 ? A * Ap : A;
            Ap = __shfl_up(A, 32); Up = __shfl_up(U, 32);
            bool c2 = quad >= 2;
            U = c2 ? fmaf(A, Up, U) : U;
            A = c2 ? A * Ap : A;
            IA[hh] = A; IU[hh] = U;                 // inclusive prefix
            float Ae = __shfl_up(A, 16), Ue = __shfl_up(U, 16);
            EA[hh] = (quad == 0) ? 1.0f : Ae;       // exclusive prefix
            EU[hh] = (quad == 0) ? 0.0f : Ue;
        }
        if (quad == 3) {
#pragma unroll
            for (int hh = 0; hh < 2; ++hh)
                Wseg[t & 1][w][hh * 16 + n16] = make_float2(IA[hh], IU[hh]);
        }

        __syncthreads();   // the ONLY barrier: Wseg (and prev carry) visible

        // ---- issue SECOND HALF of next tile's A loads ----
        float4 xf2[4];
#pragma unroll
        for (int ks = 0; ks < 2; ++ks) {
            xf2[2 * ks]     = *(const float4*)(ab + 64 + ks * 32);
            xf2[2 * ks + 1] = *(const float4*)(ab + 64 + ks * 32 + 4);
        }
        // convert first half now (data long in flight)
        af[0] = cvt8(xf1[0], xf1[1]);
        af[1] = cvt8(xf1[2], xf1[3]);

        // ---- per-lane compose (batched loads) + replay + store ----
        _Float16* dstT = dst0 + (size_t)((b * 16 + t) * 8) * 8192;
#pragma unroll
        for (int hh = 0; hh < 2; ++hh) {
            int ch = hh * 16 + n16;
            float h = carryL[t & 1][ch];
            float2 wv[7];
#pragma unroll
            for (int jj = 0; jj < 7; ++jj)
                wv[jj] = Wseg[t & 1][jj][ch];       // independent loads first
#pragma unroll
            for (int jj = 0; jj < 7; ++jj)
                if (jj < w) h = fmaf(wv[jj].x, h, wv[jj].y);
            // apply exclusive quad prefix
            h = fmaf(EA[hh], h, EU[hh]);
            // replay 4 steps + store in fragment-page layout
#pragma unroll
            for (int reg = 0; reg < 4; ++reg) {
                h = fmaf(a_s[hh][reg], h, u_s[hh][reg]);
                dstT[hh * 256 + reg * 8] = (_Float16)h;
            }
            if (w == 7 && quad == 3)
                carryL[(t + 1) & 1][ch] = h;        // tile-final h = next carry
        }

        // convert second half (flight covered by compose/replay)
        af[2] = cvt8(xf2[0], xf2[1]);
        af[3] = cvt8(xf2[2], xf2[3]);
    }
}

// ---------------------------------------------------------------------------
// k3 v5: T3/T4 port (counted vmcnt + RAW s_barrier, never drain-0 mid-loop).
//   64-row tiles, grid 1024, 256 thr (4 waves), 2 blocks/CU.
//   3-deep rings: As[3][4096] (wave-private slices) + Bs[3][8192] = 72 KB.
//   Per page k: s_waitcnt vmcnt(6) (exactly bundle k+1 left in flight) ->
//   raw s_barrier -> sched_barrier(0) -> issue bundle(k+2) -> 16 MFMA.
//   Each bundle (6 gload_lds/lane, deterministic count) flies ~2 phases.
//   Buf (k+2)%3 reuse is safe: its contents (page k-1) were consumed in
//   compute(k-1), which every wave finished before passing barrier(k).
// ---------------------------------------------------------------------------
__global__ __launch_bounds__(256, 2) void k3_mfma(
        const _Float16* __restrict__ cmbF, const _Float16* __restrict__ Wfg,
        const float* __restrict__ bfv, float* __restrict__ out) {
    __shared__ __align__(16) _Float16 As[3][4096];   // 3 x 8 KB
    __shared__ __align__(16) _Float16 Bs[3][8192];   // 3 x 16 KB

    const int tid  = threadIdx.x;
    const int lane = tid & 63;
    const int w    = tid >> 6;           // wave 0..3
    const int id   = blockIdx.x;         // 0..1023
    const int rb   = id >> 1;            // 128-row fragment-page group
    const int half = id & 1;             // which 64 rows of the page
    const int q    = lane >> 4;
    const int nn   = lane & 15;

    f32x4 acc[8];
#pragma unroll
    for (int ct = 0; ct < 8; ++ct) acc[ct] = (f32x4){0.0f, 0.0f, 0.0f, 0.0f};

    // one bundle = 6 gload_lds16/lane: As slice (2) + Bs slice (4)
#define K3_STAGE(buf, kb)                                                     \
    {                                                                         \
        const _Float16* sa = cmbF + ((size_t)rb * 8 + (kb)) * 8192            \
                           + (size_t)half * 4096 + (size_t)w * 1024           \
                           + (size_t)lane * 8;                                \
        _Float16* la = &As[buf][w * 1024];                                    \
        gload_lds16(sa, la);                                                  \
        gload_lds16(sa + 512, la + 512);                                      \
        const _Float16* sb = Wfg + (size_t)(kb) * 8192                        \
                           + (size_t)w * 2048 + (size_t)lane * 8;             \
        _Float16* lb = &Bs[buf][w * 2048];                                    \
        _Pragma("unroll")                                                     \
        for (int i = 0; i < 4; ++i)                                           \
            gload_lds16(sb + i * 512, lb + i * 512);                          \
    }

    K3_STAGE(0, 0);                      // bundle 0
    K3_STAGE(1, 1);                      // bundle 1

    for (int kb = 0; kb < 8; ++kb) {
        const int cur = kb % 3;
        // wait: bundle(kb) complete; bundle(kb+1) (6 ops) stays in flight
        if (kb < 7) asm volatile("s_waitcnt vmcnt(6)" ::: "memory");
        else        asm volatile("s_waitcnt vmcnt(0)" ::: "memory");
        __builtin_amdgcn_s_barrier();            // raw: no compiler drain
        __builtin_amdgcn_sched_barrier(0);       // pin ds_reads below (rule 18)

        if (kb < 6) K3_STAGE((kb + 2) % 3, kb + 2);   // bundle kb+2

#pragma unroll
        for (int ks = 0; ks < 2; ++ks) {
            half8 a = *(const half8*)&As[cur][w * 1024 + ks * 512 + lane * 8];
#pragma unroll
            for (int ct = 0; ct < 8; ++ct) {
                half8 bb = *(const half8*)&Bs[cur][(ks * 8 + ct) * 512 + lane * 8];
                acc[ct] = __builtin_amdgcn_mfma_f32_16x16x32_f16(a, bb, acc[ct], 0, 0, 0);
            }
        }
        __builtin_amdgcn_sched_barrier(0);       // keep phases separated
    }

    const int rbase = rb * 128 + half * 64 + w * 16 + q * 4;
#pragma unroll
    for (int ct = 0; ct < 8; ++ct) {
        int col = ct * 16 + nn;
        float bias = bfv[col];
#pragma unroll
        for (int reg = 0; reg < 4; ++reg)
            out[(size_t)(rbase + reg) * DIM + col] = acc[ct][reg] + bias;
    }
#undef K3_STAGE
}

// ---------------------------------------------------------------------------
extern "C" void kernel_launch(void* const* d_in, const int* in_sizes, int n_in,
                              void* d_out, int out_size, void* d_ws, size_t ws_size,
                              hipStream_t stream) {
    if (ws_size < WS_NEEDED) return;

    const float* x    = (const float*)d_in[0];
    const float* Wa_u = (const float*)d_in[1];
    const float* ba_u = (const float*)d_in[2];
    const float* Wi_u = (const float*)d_in[3];
    const float* bi_u = (const float*)d_in[4];
    const float* g_u  = (const float*)d_in[5];
    const float* Wa_w = (const float*)d_in[6];
    const float* ba_w = (const float*)d_in[7];
    const float* Wi_w = (const float*)d_in[8];
    const float* bi_w = (const float*)d_in[9];
    const float* g_w  = (const float*)d_in[10];
    const float* Wf   = (const float*)d_in[11];
    const float* bfv  = (const float*)d_in[12];
    float* out = (float*)d_out;

    char* ws = (char*)d_ws;
    _Float16* cmb = (_Float16*)ws;
    _Float16* Wfg = (_Float16*)(ws + WFG_OFF);

    hipLaunchKernelGGL(kfused, dim3(32, 16), dim3(512), 0, stream,
                       x, Wa_u, ba_u, Wi_u, bi_u, g_u,
                       Wa_w, ba_w, Wi_w, bi_w, g_w, Wf, Wfg, cmb);
    hipLaunchKernelGGL(k3_mfma, dim3(1024), dim3(256), 0, stream,
                       cmb, Wfg, bfv, out);
}

// Round 10
// 184.461 us; speedup vs baseline: 2.3525x; 1.0382x over previous
//
#include <hip/hip_runtime.h>
#include <hip/hip_fp16.h>
#include <cstddef>
#include <cstdint>

#define DIM 128
#define SEQ 2048
#define NB 32
#define NCH 512
#define NROWS (NB * SEQ)          // 65536

typedef _Float16 half8 __attribute__((ext_vector_type(8)));
typedef float    f32x4 __attribute__((ext_vector_type(4)));

// ws layout: cmb fp16 frag-pages [4096 pages][8192] | Wfg fp16 frag-linear
// page p = rowblk*8 + kb  (rowblk = global_row/128, kb = k/64)
// in-page: rt7*1024 + ks*512 + qq*128 + m*8 + j
//   rt7=(row>>4)&7, m=row&15, ks=(k>>5)&1, qq=(k>>3)&3, j=k&7
#define CMB_BYTES ((size_t)NROWS * NCH * 2)       // 67,108,864
#define WFG_OFF   CMB_BYTES
#define WFG_BYTES ((size_t)NCH * DIM * 2)         // 131,072
#define WS_NEEDED (WFG_OFF + WFG_BYTES)

// fast sigmoid: raw v_exp + raw v_rcp (no Newton refinement)
__device__ __forceinline__ float sigf(float v) {
    return __builtin_amdgcn_rcpf(1.0f + __builtin_amdgcn_exp2f(v * -1.44269504f));
}

// packed fp32x8 -> fp16x8 via v_cvt_pkrtz_f16_f32
__device__ __forceinline__ half8 cvt8(float4 v0, float4 v1) {
    auto p0 = __builtin_amdgcn_cvt_pkrtz(v0.x, v0.y);
    auto p1 = __builtin_amdgcn_cvt_pkrtz(v0.z, v0.w);
    auto p2 = __builtin_amdgcn_cvt_pkrtz(v1.x, v1.y);
    auto p3 = __builtin_amdgcn_cvt_pkrtz(v1.z, v1.w);
    union U { half8 h8; decltype(p0) p[4]; } u;
    u.p[0] = p0; u.p[1] = p1; u.p[2] = p2; u.p[3] = p3;
    return u.h8;
}

// async global->LDS, 16B per lane (wave-uniform LDS base + lane*16)
__device__ __forceinline__ void gload_lds16(const _Float16* g, _Float16* l) {
    __builtin_amdgcn_global_load_lds(
        (const __attribute__((address_space(1))) void*)g,
        (__attribute__((address_space(3))) void*)l,
        16, 0, 0);
}

// ---------------------------------------------------------------------------
// kfused v13 (round-6 best, byte-identical): v12 core + fused k0 pre-pass
//   (the 16 blocks with blockIdx.x==0 write Wfg = Wf pre-swizzled; only k3
//   reads Wfg and k3 launches after kfused on the same stream).
// ---------------------------------------------------------------------------
__global__ __launch_bounds__(512, 2) void kfused(
        const float* __restrict__ x,
        const float* __restrict__ Wa_u, const float* __restrict__ ba_u,
        const float* __restrict__ Wi_u, const float* __restrict__ bi_u,
        const float* __restrict__ g_u,
        const float* __restrict__ Wa_w, const float* __restrict__ ba_w,
        const float* __restrict__ Wi_w, const float* __restrict__ bi_w,
        const float* __restrict__ g_w,
        const float* __restrict__ Wf, _Float16* __restrict__ Wfg,
        _Float16* __restrict__ cmb) {
    __shared__ _Float16 Bs[8192];        // [ks(4)][nt(4)][lane(64)][8] = 16 KB
    __shared__ float2   Wseg[2][8][33];  // per-wave composite (dbuf)
    __shared__ float    carryL[2][32];   // running h per channel (dbuf)

    const int tid  = threadIdx.x;
    const int lane = tid & 63;
    const int w    = tid >> 6;           // wave 0..7 = m-tile (16 s each)
    const int quad = lane >> 4;
    const int n16  = lane & 15;

    const int b  = blockIdx.x;           // 0..31
    const int cg = blockIdx.y;           // 0..15
    const int p  = cg >> 3;              // path
    const int ebase = (cg & 7) * 32;     // 32 channels per block

    // ---- fused k0 pre-pass: blocks (0, cg) transform Wf -> Wfg ----
    if (b == 0) {
        int tg = cg * 512 + tid;          // 0..8191
#pragma unroll
        for (int i = 0; i < 8; ++i) {
            int o = tg * 8 + i;           // 65536 total
            int j    = o & 7;
            int l2   = (o >> 3) & 63;
            int q2   = l2 >> 4, m16 = l2 & 15;
            int ct   = (o >> 9) & 7;
            int ks2  = (o >> 12) & 1;
            int kb2  = o >> 13;
            int k = kb2 * 64 + ks2 * 32 + q2 * 8 + j;
            int n = ct * 16 + m16;
            Wfg[o] = (_Float16)Wf[n * NCH + k];
        }
    }

    const float* Wa  = p ? Wa_w : Wa_u;
    const float* Wi  = p ? Wi_w : Wi_u;
    const float* bap = p ? ba_w : ba_u;
    const float* bip = p ? bi_w : bi_u;
    const float* gp  = p ? g_w  : g_u;

    // ---- stage Bs once: slot sl = ks*256 + nt*64 + l (1024 slots, 2/thread)
    for (int sl = tid; sl < 1024; sl += 512) {
        int l  = sl & 63;
        int nt = (sl >> 6) & 3;
        int ks = sl >> 8;
        int qq = l >> 4, nn = l & 15;
        int e = ebase + (nt & 1) * 16 + nn;
        const float* Wp = (nt >> 1) ? Wi : Wa;
        const float* src = Wp + (size_t)e * DIM + ks * 32 + qq * 8;
        float4 v0 = *(const float4*)src;
        float4 v1 = *(const float4*)(src + 4);
        *(half8*)&Bs[sl * 8] = cvt8(v0, v1);
    }

    // per-thread channel params (hh = 0/1 -> ch = hh*16 + n16)
    const float NL2E = -1.44269504f;
    float rba[2], rbi[2], ral[2], rba2[2];
#pragma unroll
    for (int hh = 0; hh < 2; ++hh) {
        int e = ebase + hh * 16 + n16;
        rba[hh] = bap[e];
        rbi[hh] = bip[e];
        ral[hh] = sigf(gp[e]);
        rba2[hh] = rba[hh] * NL2E;
    }
    if (tid < 32) carryL[0][tid] = 0.0f;

    // incremental recency weight: sc(s) = exp(3s/2047)
    float scb = __expf((float)(w * 16 + quad * 4) * (3.0f / 2047.0f));
    const float r1    = __expf(3.0f / 2047.0f);
    const float r2    = r1 * r1;
    const float r3    = r2 * r1;
    const float cs128 = __expf(128.0f * 3.0f / 2047.0f);

    // A-row for this lane: s_local = w*16 + n16 (= MFMA m index)
    const float* xbase = x + ((size_t)b * SEQ + (size_t)(w * 16 + n16)) * DIM + quad * 8;
    // fragment-page store base: page = (b*16+t)*8 + (cg>>1)
    _Float16* dst0 = cmb + (size_t)(cg >> 1) * 8192 + (size_t)w * 1024
                   + (size_t)(cg & 1) * 512
                   + (size_t)quad * 32 + (size_t)(n16 >> 3) * 128 + (n16 & 7);

    __syncthreads();                     // Bs + carry init visible

    // ---- prologue: registerize B-frags for ks 0,1 (constant all tiles) ----
    half8 bfr[8];
#pragma unroll
    for (int ks = 0; ks < 2; ++ks)
#pragma unroll
        for (int nt = 0; nt < 4; ++nt)
            bfr[ks * 4 + nt] = *(const half8*)&Bs[(ks * 256 + nt * 64 + lane) * 8];

    // ---- prologue: load + convert tile 0's A-frags ----
    half8 af[4];
    {
        float4 xf0[8];
#pragma unroll
        for (int ks = 0; ks < 4; ++ks) {
            xf0[2 * ks]     = *(const float4*)(xbase + ks * 32);
            xf0[2 * ks + 1] = *(const float4*)(xbase + ks * 32 + 4);
        }
#pragma unroll
        for (int ks = 0; ks < 4; ++ks)
            af[ks] = cvt8(xf0[2 * ks], xf0[2 * ks + 1]);
    }

    for (int t = 0; t < 16; ++t) {
        // ---- MFMA: 4 n-tiles, K=128; ks 0,1 B from regs, ks 2,3 from LDS --
        f32x4 acc[4];
#pragma unroll
        for (int nt = 0; nt < 4; ++nt) acc[nt] = (f32x4){0.f, 0.f, 0.f, 0.f};
#pragma unroll
        for (int ks = 0; ks < 4; ++ks) {
            half8 a = af[ks];
#pragma unroll
            for (int nt = 0; nt < 4; ++nt) {
                half8 bb = (ks < 2)
                    ? bfr[ks * 4 + nt]
                    : *(const half8*)&Bs[(ks * 256 + nt * 64 + lane) * 8];
                acc[nt] = __builtin_amdgcn_mfma_f32_16x16x32_f16(a, bb, acc[nt], 0, 0, 0);
            }
        }

        // ---- issue FIRST HALF of next tile's A loads (long flight) ----
        const float* ab = xbase + (size_t)((t + 1) & 15) * 128 * DIM;
        float4 xf1[4];
#pragma unroll
        for (int ks = 0; ks < 2; ++ks) {
            xf1[2 * ks]     = *(const float4*)(ab + ks * 32);
            xf1[2 * ks + 1] = *(const float4*)(ab + ks * 32 + 4);
        }

        // ---- gates + 4-step affine compose (2 channels) ----
        float sc[4], sc2[4];
        if (p) { sc[0] = scb; sc[1] = scb * r1; sc[2] = scb * r2; sc[3] = scb * r3; }
        else   { sc[0] = sc[1] = sc[2] = sc[3] = 1.0f; }
        scb *= cs128;
#pragma unroll
        for (int reg = 0; reg < 4; ++reg) sc2[reg] = sc[reg] * NL2E;

        float a_s[2][4], u_s[2][4];
        float IA[2], IU[2], EA[2], EU[2];
#pragma unroll
        for (int hh = 0; hh < 2; ++hh) {
            float A4 = 1.0f, U4 = 0.0f;
#pragma unroll
            for (int reg = 0; reg < 4; ++reg) {
                float pi  = fmaf(acc[2 + hh][reg], sc[reg], rbi[hh]);
                float ea  = __builtin_amdgcn_exp2f(fmaf(acc[hh][reg], sc2[reg], rba2[hh]));
                float rst = __builtin_amdgcn_rcpf(1.0f + ea);
                float ig  = sigf(pi);
                float a   = ral[hh] * __builtin_amdgcn_exp2f(-rst * 1.5849625007211562f);
                float m   = fmaxf(fmaf(-a, a, 1.0f), 0.0f);
                float u   = __builtin_amdgcn_sqrtf(m) * (ig * pi);
                a_s[hh][reg] = a; u_s[hh][reg] = u;
                A4 *= a;
                U4 = fmaf(a, U4, u);
            }
            // Kogge-Stone inclusive scan over quads (lane stride 16)
            float A = A4, U = U4;
            float Ap = __shfl_up(A, 16); float Up = __shfl_up(U, 16);
            bool c1 = quad >= 1;
            U = c1 ? fmaf(A, Up, U) : U;
            A = c1 ? A * Ap : A;
            Ap = __shfl_up(A, 32); Up = __shfl_up(U, 32);
            bool c2 = quad >= 2;
            U = c2 ? fmaf(A, Up, U) : U;
            A = c2 ? A * Ap : A;
            IA[hh] = A; IU[hh] = U;                 // inclusive prefix
            float Ae = __shfl_up(A, 16), Ue = __shfl_up(U, 16);
            EA[hh] = (quad == 0) ? 1.0f : Ae;       // exclusive prefix
            EU[hh] = (quad == 0) ? 0.0f : Ue;
        }
        if (quad == 3) {
#pragma unroll
            for (int hh = 0; hh < 2; ++hh)
                Wseg[t & 1][w][hh * 16 + n16] = make_float2(IA[hh], IU[hh]);
        }

        __syncthreads();   // the ONLY barrier: Wseg (and prev carry) visible

        // ---- issue SECOND HALF of next tile's A loads ----
        float4 xf2[4];
#pragma unroll
        for (int ks = 0; ks < 2; ++ks) {
            xf2[2 * ks]     = *(const float4*)(ab + 64 + ks * 32);
            xf2[2 * ks + 1] = *(const float4*)(ab + 64 + ks * 32 + 4);
        }
        // convert first half now (data long in flight)
        af[0] = cvt8(xf1[0], xf1[1]);
        af[1] = cvt8(xf1[2], xf1[3]);

        // ---- per-lane compose (batched loads) + replay + store ----
        _Float16* dstT = dst0 + (size_t)((b * 16 + t) * 8) * 8192;
#pragma unroll
        for (int hh = 0; hh < 2; ++hh) {
            int ch = hh * 16 + n16;
            float h = carryL[t & 1][ch];
            float2 wv[7];
#pragma unroll
            for (int jj = 0; jj < 7; ++jj)
                wv[jj] = Wseg[t & 1][jj][ch];       // independent loads first
#pragma unroll
            for (int jj = 0; jj < 7; ++jj)
                if (jj < w) h = fmaf(wv[jj].x, h, wv[jj].y);
            // apply exclusive quad prefix
            h = fmaf(EA[hh], h, EU[hh]);
            // replay 4 steps + store in fragment-page layout
#pragma unroll
            for (int reg = 0; reg < 4; ++reg) {
                h = fmaf(a_s[hh][reg], h, u_s[hh][reg]);
                dstT[hh * 256 + reg * 8] = (_Float16)h;
            }
            if (w == 7 && quad == 3)
                carryL[(t + 1) & 1][ch] = h;        // tile-final h = next carry
        }

        // convert second half (flight covered by compose/replay)
        af[2] = cvt8(xf2[0], xf2[1]);
        af[3] = cvt8(xf2[2], xf2[3]);
    }
}

// ---------------------------------------------------------------------------
// k3 v6: v2's proven structure (As+Bs LDS, gload_lds width-16, 2-phase dbuf,
//   one barrier/page) with 512 threads = 8 waves -> 16 waves/CU (4/SIMD),
//   double v2's occupancy. Per wave: 1 m-tile (16 rows), 16 MFMA/page.
//   Staging: 4 gload_lds16/thread/page (2 As + 2 Bs). LDS 64 KB, 2 blk/CU.
// ---------------------------------------------------------------------------
__global__ __launch_bounds__(512, 2) void k3_mfma(
        const _Float16* __restrict__ cmbF, const _Float16* __restrict__ Wfg,
        const float* __restrict__ bfv, float* __restrict__ out) {
    __shared__ _Float16 As[2][8192];     // 2 x 16 KB
    __shared__ _Float16 Bs[2][8192];     // 2 x 16 KB

    const int tid  = threadIdx.x;
    const int lane = tid & 63;
    const int w    = tid >> 6;           // wave 0..7 = rt7 (16-row slice)
    const int rb   = blockIdx.x;         // row-block 0..511
    const int q    = lane >> 4;
    const int nn   = lane & 15;

    f32x4 acc[8];
#pragma unroll
    for (int ct = 0; ct < 8; ++ct) acc[ct] = (f32x4){0.0f, 0.0f, 0.0f, 0.0f};

    // page = 8192 elems; wave w covers [p*4096 + w*512, +512) per pass p=0,1
#define K3_STAGE(buf, kb)                                                     \
    {                                                                         \
        const _Float16* sa = cmbF + ((size_t)rb * 8 + (kb)) * 8192            \
                           + (size_t)w * 512 + (size_t)lane * 8;              \
        const _Float16* sb = Wfg + (size_t)(kb) * 8192                        \
                           + (size_t)w * 512 + (size_t)lane * 8;              \
        _Float16* la = &As[buf][w * 512];                                     \
        _Float16* lb = &Bs[buf][w * 512];                                     \
        gload_lds16(sa, la);                                                  \
        gload_lds16(sa + 4096, la + 4096);                                    \
        gload_lds16(sb, lb);                                                  \
        gload_lds16(sb + 4096, lb + 4096);                                    \
    }

    K3_STAGE(0, 0);
    __syncthreads();                     // implies vmcnt(0) drain

    for (int kb = 0; kb < 8; ++kb) {
        const int cur = kb & 1;
        if (kb < 7) K3_STAGE(cur ^ 1, kb + 1);

#pragma unroll
        for (int ks = 0; ks < 2; ++ks) {
            half8 a = *(const half8*)&As[cur][w * 1024 + ks * 512 + lane * 8];
#pragma unroll
            for (int ct = 0; ct < 8; ++ct) {
                half8 bb = *(const half8*)&Bs[cur][(ks * 8 + ct) * 512 + lane * 8];
                acc[ct] = __builtin_amdgcn_mfma_f32_16x16x32_f16(a, bb, acc[ct], 0, 0, 0);
            }
        }
        __syncthreads();                 // next buf staged + cur free for reuse
    }

    const int rbase = rb * 128 + w * 16 + q * 4;
#pragma unroll
    for (int ct = 0; ct < 8; ++ct) {
        int col = ct * 16 + nn;
        float bias = bfv[col];
#pragma unroll
        for (int reg = 0; reg < 4; ++reg)
            out[(size_t)(rbase + reg) * DIM + col] = acc[ct][reg] + bias;
    }
#undef K3_STAGE
}

// ---------------------------------------------------------------------------
extern "C" void kernel_launch(void* const* d_in, const int* in_sizes, int n_in,
                              void* d_out, int out_size, void* d_ws, size_t ws_size,
                              hipStream_t stream) {
    if (ws_size < WS_NEEDED) return;

    const float* x    = (const float*)d_in[0];
    const float* Wa_u = (const float*)d_in[1];
    const float* ba_u = (const float*)d_in[2];
    const float* Wi_u = (const float*)d_in[3];
    const float* bi_u = (const float*)d_in[4];
    const float* g_u  = (const float*)d_in[5];
    const float* Wa_w = (const float*)d_in[6];
    const float* ba_w = (const float*)d_in[7];
    const float* Wi_w = (const float*)d_in[8];
    const float* bi_w = (const float*)d_in[9];
    const float* g_w  = (const float*)d_in[10];
    const float* Wf   = (const float*)d_in[11];
    const float* bfv  = (const float*)d_in[12];
    float* out = (float*)d_out;

    char* ws = (char*)d_ws;
    _Float16* cmb = (_Float16*)ws;
    _Float16* Wfg = (_Float16*)(ws + WFG_OFF);

    hipLaunchKernelGGL(kfused, dim3(32, 16), dim3(512), 0, stream,
                       x, Wa_u, ba_u, Wi_u, bi_u, g_u,
                       Wa_w, ba_w, Wi_w, bi_w, g_w, Wf, Wfg, cmb);
    hipLaunchKernelGGL(k3_mfma, dim3(512), dim3(512), 0, stream,
                       cmb, Wfg, bfv, out);
}